// Round 2
// baseline (335.069 us; speedup 1.0000x reference)
//
#include <hip/hip_runtime.h>
#include <math.h>

// Problem constants
#define B_ 16
#define C_ 256
#define H_ 64
#define W_ 64
#define G_ 8
#define CG_ 32
#define HID_ 64

// ---------------- Kernel 1: global average pool -> pooled[B,C] ----------------
__global__ void pool_kernel(const float* __restrict__ x, float* __restrict__ pooled) {
    int idx = blockIdx.x;  // b*C + c
    const float4* src = (const float4*)(x + (size_t)idx * (H_ * W_));
    float s = 0.f;
#pragma unroll
    for (int i = 0; i < 4; ++i) {
        float4 v = src[threadIdx.x + i * 256];
        s += v.x + v.y + v.z + v.w;
    }
#pragma unroll
    for (int off = 32; off > 0; off >>= 1) s += __shfl_down(s, off, 64);
    __shared__ float wsum[4];
    if ((threadIdx.x & 63) == 0) wsum[threadIdx.x >> 6] = s;
    __syncthreads();
    if (threadIdx.x == 0)
        pooled[idx] = (wsum[0] + wsum[1] + wsum[2] + wsum[3]) * (1.0f / 4096.0f);
}

// ---------------- Kernel 2: MLPs -> angles[B,G], mod[B,C] ----------------
__global__ void mlp_kernel(const float* __restrict__ pooled,
                           const float* __restrict__ ap_w1, const float* __restrict__ ap_b1,
                           const float* __restrict__ ap_w2, const float* __restrict__ ap_b2,
                           const float* __restrict__ mw1, const float* __restrict__ mb1,
                           const float* __restrict__ mw2, const float* __restrict__ mb2,
                           float* __restrict__ angles, float* __restrict__ modg) {
    int b = blockIdx.x, tid = threadIdx.x;
    __shared__ float sp[C_], ha[HID_], hm[HID_];
    sp[tid] = pooled[b * C_ + tid];
    __syncthreads();
    if (tid < 64) {
        const float* wr = ap_w1 + tid * C_;
        float s = ap_b1[tid];
        for (int c = 0; c < C_; ++c) s = fmaf(sp[c], wr[c], s);
        ha[tid] = fmaxf(s, 0.f);
    } else if (tid < 128) {
        int t = tid - 64;
        const float* wr = mw1 + t * C_;
        float s = mb1[t];
        for (int c = 0; c < C_; ++c) s = fmaf(sp[c], wr[c], s);
        hm[t] = fmaxf(s, 0.f);
    }
    __syncthreads();
    if (tid < G_) {
        const float* wr = ap_w2 + tid * HID_;
        float s = ap_b2[tid];
        for (int i = 0; i < HID_; ++i) s = fmaf(ha[i], wr[i], s);
        angles[b * G_ + tid] = tanhf(s) * 0.78539816339744830962f;  // pi/4
    }
    {
        const float* wr = mw2 + tid * HID_;
        float s = mb2[tid];
        for (int i = 0; i < HID_; ++i) s = fmaf(hm[i], wr[i], s);
        modg[b * C_ + tid] = 1.0f / (1.0f + expf(-s));
    }
}

// ---------------- Kernel 3: bilinear rotation -> rot[b][g][ci][k][co] ----------------
// Matches reference: x_rot = xx*c + yy*s + cx ; y_rot = -xx*s + yy*c + cy ;
// x0 = clip(floor(x_rot),0,K-2) etc. (extrapolating weights kept as-is)
__global__ void rot_kernel(const float* __restrict__ base, const float* __restrict__ angles,
                           float* __restrict__ rot) {
    int e = blockIdx.x * 256 + threadIdx.x;  // total B*G*32*32*9 = 1179648
    int co = e & 31;
    int t = e >> 5;
    int k = t % 9;
    t /= 9;
    int ci = t & 31;
    t >>= 5;
    int g = t & 7;
    int b = t >> 3;

    float ang = angles[b * G_ + g];
    float cc = cosf(ang), ss = sinf(ang);
    int i = k / 3, j = k % 3;
    float fx = (float)(j - 1), fy = (float)(i - 1);
    float xr = fx * cc + fy * ss + 1.0f;
    float yr = -fx * ss + fy * cc + 1.0f;
    float x0f = fminf(fmaxf(floorf(xr), 0.f), 1.f);
    float y0f = fminf(fmaxf(floorf(yr), 0.f), 1.f);
    float w00 = (x0f + 1.f - xr) * (y0f + 1.f - yr);
    float w01 = (x0f + 1.f - xr) * (yr - y0f);
    float w10 = (xr - x0f) * (y0f + 1.f - yr);
    float w11 = (xr - x0f) * (yr - y0f);
    int x0 = (int)x0f, y0 = (int)y0f;

    const float* bk = base + (((size_t)(g * CG_ + co) * CG_ + ci) * 9);
    float v = w00 * bk[y0 * 3 + x0] + w01 * bk[(y0 + 1) * 3 + x0] +
              w10 * bk[y0 * 3 + x0 + 1] + w11 * bk[(y0 + 1) * 3 + x0 + 1];
    // layout: [b][g][ci][k][co]
    rot[((size_t)(b * G_ + g) * CG_ + ci) * 288 + k * 32 + co] = v;
}

// ---------------- Kernel 4: grouped conv + SE gate ----------------
// grid: (B*G, H/2). Block 256. Each block: one (b,g), 2 output rows, all 32 co.
// thread: co = tid>>3 (0..31), pg = tid&7 -> cols [pg*8, pg*8+8)
__global__ __launch_bounds__(256, 2) void conv_kernel(const float* __restrict__ x,
                                                      const float* __restrict__ rot,
                                                      const float* __restrict__ modg,
                                                      float* __restrict__ out) {
    __shared__ float sW[32 * 9 * 32];   // [ci][k][co]  36864 B
    __shared__ float sX[32][4][68];     // [ci][row][1+col], halos at 0 and 65; 34816 B
    int bg = blockIdx.x;
    int b = bg >> 3, g = bg & 7;
    int row0 = blockIdx.y * 2;
    int tid = threadIdx.x;

    // stage weights (flat float4 copy: 2304 float4)
    const float4* wsrc = (const float4*)(rot + (size_t)bg * 9216);
    float4* wdst = (float4*)sW;
#pragma unroll
    for (int i = 0; i < 9; ++i) wdst[tid + i * 256] = wsrc[tid + i * 256];

    // stage input rows row0-1 .. row0+2 for all 32 ci (zero out-of-bounds rows)
#pragma unroll
    for (int j = 0; j < 8; ++j) {
        int idx = tid + j * 256;          // 2048 float4 total
        int col4 = idx & 15;              // 16 float4 per 64-col row
        int r = (idx >> 4) & 3;
        int ci = idx >> 6;
        int row = row0 - 1 + r;
        float4 v = make_float4(0.f, 0.f, 0.f, 0.f);
        if (row >= 0 && row < H_)
            v = ((const float4*)(x + (((size_t)(b * C_ + g * CG_ + ci) * H_ + row) * W_)))[col4];
        float* d = &sX[ci][r][1 + col4 * 4];
        d[0] = v.x; d[1] = v.y; d[2] = v.z; d[3] = v.w;
    }
    // zero the column halos
    {
        int ci = tid >> 3, r = (tid >> 1) & 3;
        sX[ci][r][(tid & 1) ? 65 : 0] = 0.f;
    }
    __syncthreads();

    int co = tid >> 3;
    int c0 = (tid & 7) * 8;
    float gmod = modg[b * C_ + g * CG_ + co];

    float acc[2][8];
#pragma unroll
    for (int r = 0; r < 2; ++r)
#pragma unroll
        for (int cc = 0; cc < 8; ++cc) acc[r][cc] = 0.f;

    for (int ci = 0; ci < 32; ++ci) {
        float w[9];
#pragma unroll
        for (int k = 0; k < 9; ++k) w[k] = sW[ci * 288 + k * 32 + co];
        float xin[4][10];
#pragma unroll
        for (int r = 0; r < 4; ++r)
#pragma unroll
            for (int j = 0; j < 10; ++j) xin[r][j] = sX[ci][r][c0 + j];
#pragma unroll
        for (int r = 0; r < 2; ++r)
#pragma unroll
            for (int kh = 0; kh < 3; ++kh)
#pragma unroll
                for (int kw = 0; kw < 3; ++kw)
#pragma unroll
                    for (int cc = 0; cc < 8; ++cc)
                        acc[r][cc] = fmaf(w[kh * 3 + kw], xin[r + kh][cc + kw], acc[r][cc]);
    }

#pragma unroll
    for (int r = 0; r < 2; ++r) {
        float4 o0 = make_float4(acc[r][0] * gmod, acc[r][1] * gmod, acc[r][2] * gmod, acc[r][3] * gmod);
        float4 o1 = make_float4(acc[r][4] * gmod, acc[r][5] * gmod, acc[r][6] * gmod, acc[r][7] * gmod);
        float4* op = (float4*)(out + (((size_t)(b * C_ + g * CG_ + co) * H_ + row0 + r) * W_ + c0));
        op[0] = o0;
        op[1] = o1;
    }
}

extern "C" void kernel_launch(void* const* d_in, const int* in_sizes, int n_in,
                              void* d_out, int out_size, void* d_ws, size_t ws_size,
                              hipStream_t stream) {
    const float* x      = (const float*)d_in[0];
    const float* basek  = (const float*)d_in[1];
    const float* ap_w1  = (const float*)d_in[2];
    const float* ap_b1  = (const float*)d_in[3];
    const float* ap_w2  = (const float*)d_in[4];
    const float* ap_b2  = (const float*)d_in[5];
    const float* mw1    = (const float*)d_in[6];
    const float* mb1    = (const float*)d_in[7];
    const float* mw2    = (const float*)d_in[8];
    const float* mb2    = (const float*)d_in[9];
    float* out = (float*)d_out;

    // Non-overlapping workspace layout (floats):
    //   pooled: [0,     4096)
    //   angles: [4096,  4224)  (pad to 8192)
    //   modg:   [8192, 12288)
    //   rot:    [12288, 12288+1179648)   -- byte offset 49152, 16B aligned
    float* wsf    = (float*)d_ws;
    float* pooled = wsf;
    float* angles = wsf + 4096;
    float* modg   = wsf + 8192;
    float* rot    = wsf + 12288;

    pool_kernel<<<B_ * C_, 256, 0, stream>>>(x, pooled);
    mlp_kernel<<<B_, 256, 0, stream>>>(pooled, ap_w1, ap_b1, ap_w2, ap_b2,
                                       mw1, mb1, mw2, mb2, angles, modg);
    rot_kernel<<<(B_ * G_ * CG_ * CG_ * 9) / 256, 256, 0, stream>>>(basek, angles, rot);
    dim3 cgrid(B_ * G_, H_ / 2);
    conv_kernel<<<cgrid, 256, 0, stream>>>(x, rot, modg, out);
}

// Round 3
// 166.392 us; speedup vs baseline: 2.0137x; 2.0137x over previous
//
#include <hip/hip_runtime.h>
#include <math.h>

// Problem constants
#define B_ 16
#define C_ 256
#define H_ 64
#define W_ 64
#define G_ 8
#define CG_ 32
#define HID_ 64

typedef __attribute__((ext_vector_type(8))) short short8;
typedef __attribute__((ext_vector_type(4))) float floatx4;

__device__ inline unsigned short f2bf(float f) {
    union { float f; unsigned u; } v; v.f = f;
    unsigned r = v.u + 0x7fffu + ((v.u >> 16) & 1u);  // round-to-nearest-even
    return (unsigned short)(r >> 16);
}

// ---------------- Kernel 1: global average pool -> pooled[B,C] ----------------
__global__ void pool_kernel(const float* __restrict__ x, float* __restrict__ pooled) {
    int idx = blockIdx.x;  // b*C + c
    const float4* src = (const float4*)(x + (size_t)idx * (H_ * W_));
    float s = 0.f;
#pragma unroll
    for (int i = 0; i < 4; ++i) {
        float4 v = src[threadIdx.x + i * 256];
        s += v.x + v.y + v.z + v.w;
    }
#pragma unroll
    for (int off = 32; off > 0; off >>= 1) s += __shfl_down(s, off, 64);
    __shared__ float wsum[4];
    if ((threadIdx.x & 63) == 0) wsum[threadIdx.x >> 6] = s;
    __syncthreads();
    if (threadIdx.x == 0)
        pooled[idx] = (wsum[0] + wsum[1] + wsum[2] + wsum[3]) * (1.0f / 4096.0f);
}

// ---------------- Kernel 2: MLPs -> angles[B,G], mod[B,C] ----------------
__global__ void mlp_kernel(const float* __restrict__ pooled,
                           const float* __restrict__ ap_w1, const float* __restrict__ ap_b1,
                           const float* __restrict__ ap_w2, const float* __restrict__ ap_b2,
                           const float* __restrict__ mw1, const float* __restrict__ mb1,
                           const float* __restrict__ mw2, const float* __restrict__ mb2,
                           float* __restrict__ angles, float* __restrict__ modg) {
    int b = blockIdx.x, tid = threadIdx.x;
    __shared__ float sp[C_], ha[HID_], hm[HID_];
    sp[tid] = pooled[b * C_ + tid];
    __syncthreads();
    if (tid < 64) {
        const float* wr = ap_w1 + tid * C_;
        float s = ap_b1[tid];
        for (int c = 0; c < C_; ++c) s = fmaf(sp[c], wr[c], s);
        ha[tid] = fmaxf(s, 0.f);
    } else if (tid < 128) {
        int t = tid - 64;
        const float* wr = mw1 + t * C_;
        float s = mb1[t];
        for (int c = 0; c < C_; ++c) s = fmaf(sp[c], wr[c], s);
        hm[t] = fmaxf(s, 0.f);
    }
    __syncthreads();
    if (tid < G_) {
        const float* wr = ap_w2 + tid * HID_;
        float s = ap_b2[tid];
        for (int i = 0; i < HID_; ++i) s = fmaf(ha[i], wr[i], s);
        angles[b * G_ + tid] = tanhf(s) * 0.78539816339744830962f;  // pi/4
    }
    {
        const float* wr = mw2 + tid * HID_;
        float s = mb2[tid];
        for (int i = 0; i < HID_; ++i) s = fmaf(hm[i], wr[i], s);
        modg[b * C_ + tid] = 1.0f / (1.0f + expf(-s));
    }
}

// ---------------- Kernel 3: bilinear rotation -> rotw bf16 [bg][k9][co][ci] ----------------
__global__ void rot_kernel(const float* __restrict__ base, const float* __restrict__ angles,
                           unsigned short* __restrict__ rotw) {
    int e = blockIdx.x * 256 + threadIdx.x;  // total B*G*9*32*32 = 1179648
    int ci = e & 31;
    int co = (e >> 5) & 31;
    int t = e >> 10;       // bg*9 + k
    int k = t % 9;
    int bg = t / 9;
    int b = bg >> 3, g = bg & 7;

    float ang = angles[b * G_ + g];
    float cc = cosf(ang), ss = sinf(ang);
    int i = k / 3, j = k % 3;
    float fx = (float)(j - 1), fy = (float)(i - 1);
    float xr = fx * cc + fy * ss + 1.0f;
    float yr = -fx * ss + fy * cc + 1.0f;
    float x0f = fminf(fmaxf(floorf(xr), 0.f), 1.f);
    float y0f = fminf(fmaxf(floorf(yr), 0.f), 1.f);
    float w00 = (x0f + 1.f - xr) * (y0f + 1.f - yr);
    float w01 = (x0f + 1.f - xr) * (yr - y0f);
    float w10 = (xr - x0f) * (y0f + 1.f - yr);
    float w11 = (xr - x0f) * (yr - y0f);
    int x0 = (int)x0f, y0 = (int)y0f;

    const float* bk = base + (((size_t)(g * CG_ + co) * CG_ + ci) * 9);
    float v = w00 * bk[y0 * 3 + x0] + w01 * bk[(y0 + 1) * 3 + x0] +
              w10 * bk[y0 * 3 + x0 + 1] + w11 * bk[(y0 + 1) * 3 + x0 + 1];
    rotw[e] = f2bf(v);
}

// ---------------- Kernel 4: MFMA implicit-GEMM grouped conv + SE gate ----------------
// grid: (128 bg, 8 strips of 8 rows). Block 256 = 4 waves.
// Per block: C[32co x 512px] = sum over 9 taps of W_k[32x32ci] * Xshift_k[32ci x 512px]
// sX layout [row 0..9][col 0..65][ci 0..31] bf16 -> B-frag = contiguous ds_read_b128
// sW layout [k9][co][ci] bf16                    -> A-frag = contiguous ds_read_b128
__global__ __launch_bounds__(256, 2) void conv_mfma(const float* __restrict__ x,
                                                    const unsigned short* __restrict__ rotw,
                                                    const float* __restrict__ modg,
                                                    float* __restrict__ out) {
    __shared__ __align__(16) unsigned short sW[9 * 32 * 32];    // 18432 B
    __shared__ __align__(16) unsigned short sX[10 * 66 * 32];   // 42240 B
    __shared__ float smod[32];
    int bg = blockIdx.x;
    int b = bg >> 3, g = bg & 7;
    int r0 = blockIdx.y * 8;
    int tid = threadIdx.x;

    // ---- stage weights: 9216 bf16 = 1152 float4 ----
    {
        const float4* src = (const float4*)(rotw + (size_t)bg * 9216);
        float4* dst = (float4*)sW;
#pragma unroll
        for (int i = 0; i < 5; ++i) {
            int idx = tid + i * 256;
            if (idx < 1152) dst[idx] = src[idx];
        }
    }
    if (tid < 32) smod[tid] = modg[b * C_ + g * CG_ + tid];

    // ---- stage x rows r0-1 .. r0+8, bf16, transposed to [r][c][ci] ----
    {
        int ci = tid & 31;
        int cellbase = tid >> 5;  // 0..7
#pragma unroll
        for (int i = 0; i < 20; ++i) {
            int cell = cellbase + i * 8;    // 0..159
            int c4 = cell & 15, r = cell >> 4;
            int grow = r0 - 1 + r;
            float4 v = make_float4(0.f, 0.f, 0.f, 0.f);
            if (grow >= 0 && grow < H_)
                v = *(const float4*)(x + (((size_t)(b * C_ + g * CG_ + ci) * H_ + grow) * W_ + c4 * 4));
            int base = (r * 66 + 1 + c4 * 4) * 32 + ci;
            sX[base] = f2bf(v.x);
            sX[base + 32] = f2bf(v.y);
            sX[base + 64] = f2bf(v.z);
            sX[base + 96] = f2bf(v.w);
        }
        // column halos (c=0 and c=65) = 0
#pragma unroll
        for (int i = 0; i < 3; ++i) {
            int idx = tid + i * 256;
            if (idx < 640) {
                int ci2 = idx & 31;
                int t2 = idx >> 5;          // 0..19
                int side = t2 & 1, r = t2 >> 1;
                sX[(r * 66 + side * 65) * 32 + ci2] = 0;
            }
        }
    }
    __syncthreads();

    int lane = tid & 63;
    int wv = tid >> 6;        // 0..3 -> rows wv*2, wv*2+1
    int nlo = lane & 15;      // px within N-tile / co within M-tile (A)
    int quad = lane >> 4;     // k-chunk selector

    floatx4 acc0[8], acc1[8];
#pragma unroll
    for (int nt = 0; nt < 8; ++nt) {
        acc0[nt] = (floatx4){0.f, 0.f, 0.f, 0.f};
        acc1[nt] = (floatx4){0.f, 0.f, 0.f, 0.f};
    }

#pragma unroll
    for (int k9 = 0; k9 < 9; ++k9) {
        const int dy = k9 / 3 - 1, dx = k9 % 3 - 1;
        short8 a0 = *(const short8*)&sW[((k9 * 32) + nlo) * 32 + quad * 8];
        short8 a1 = *(const short8*)&sW[((k9 * 32) + 16 + nlo) * 32 + quad * 8];
#pragma unroll
        for (int nt = 0; nt < 8; ++nt) {
            int rr = wv * 2 + (nt >> 2) + 1 + dy;        // 0..9
            int cc = (nt & 3) * 16 + nlo + 1 + dx;       // 0..65
            short8 bf = *(const short8*)&sX[(rr * 66 + cc) * 32 + quad * 8];
            acc0[nt] = __builtin_amdgcn_mfma_f32_16x16x32_bf16(a0, bf, acc0[nt], 0, 0, 0);
            acc1[nt] = __builtin_amdgcn_mfma_f32_16x16x32_bf16(a1, bf, acc1[nt], 0, 0, 0);
        }
    }

    // ---- epilogue: D col = lane&15 (px), row = quad*4+reg (co) ----
    float gm[2][4];
#pragma unroll
    for (int mt = 0; mt < 2; ++mt)
#pragma unroll
        for (int reg = 0; reg < 4; ++reg) gm[mt][reg] = smod[mt * 16 + quad * 4 + reg];

#pragma unroll
    for (int nt = 0; nt < 8; ++nt) {
        int row = r0 + wv * 2 + (nt >> 2);
        int col = (nt & 3) * 16 + nlo;
#pragma unroll
        for (int reg = 0; reg < 4; ++reg) {
            int co0 = quad * 4 + reg;
            out[((size_t)(b * C_ + g * CG_ + co0) * H_ + row) * W_ + col] = acc0[nt][reg] * gm[0][reg];
            int co1 = 16 + quad * 4 + reg;
            out[((size_t)(b * C_ + g * CG_ + co1) * H_ + row) * W_ + col] = acc1[nt][reg] * gm[1][reg];
        }
    }
}

extern "C" void kernel_launch(void* const* d_in, const int* in_sizes, int n_in,
                              void* d_out, int out_size, void* d_ws, size_t ws_size,
                              hipStream_t stream) {
    const float* x      = (const float*)d_in[0];
    const float* basek  = (const float*)d_in[1];
    const float* ap_w1  = (const float*)d_in[2];
    const float* ap_b1  = (const float*)d_in[3];
    const float* ap_w2  = (const float*)d_in[4];
    const float* ap_b2  = (const float*)d_in[5];
    const float* mw1    = (const float*)d_in[6];
    const float* mb1    = (const float*)d_in[7];
    const float* mw2    = (const float*)d_in[8];
    const float* mb2    = (const float*)d_in[9];
    float* out = (float*)d_out;

    // Workspace (floats): pooled [0,4096), angles [4096,4224), modg [8192,12288),
    // rotw (bf16) at float-offset 12288 = byte 49152 (16B aligned), 2359296 B.
    float* wsf    = (float*)d_ws;
    float* pooled = wsf;
    float* angles = wsf + 4096;
    float* modg   = wsf + 8192;
    unsigned short* rotw = (unsigned short*)(wsf + 12288);

    pool_kernel<<<B_ * C_, 256, 0, stream>>>(x, pooled);
    mlp_kernel<<<B_, 256, 0, stream>>>(pooled, ap_w1, ap_b1, ap_w2, ap_b2,
                                       mw1, mb1, mw2, mb2, angles, modg);
    rot_kernel<<<(B_ * G_ * CG_ * CG_ * 9) / 256, 256, 0, stream>>>(basek, angles, rotw);
    dim3 cgrid(B_ * G_, H_ / 8);
    conv_mfma<<<cgrid, 256, 0, stream>>>(x, rotw, modg, out);
}